// Round 3
// baseline (275.271 us; speedup 1.0000x reference)
//
#include <hip/hip_runtime.h>
#include <cstdint>
#include <cstddef>

#pragma clang fp contract(off)

#define B_IMG 64
#define N_BOX 4032
#define C_CLS 80
#define MAX_PER_CLASS 50
#define MAX_TOTAL 50
#define CAP1 192
#define FCAP 512
#define T1 0.9546f

// Fallback tier lower bounds (descending); tier t covers [d_flo[t], prev), last is exactly 0.4f.
__device__ __constant__ float d_flo[5] = {0.81f, 0.6724f, 0.5476f, 0.4356f, 0.4f};

__device__ __forceinline__ float bcastf(float v, int l) {
    return __uint_as_float((unsigned)__builtin_amdgcn_readlane((int)__float_as_uint(v), l));
}
__device__ __forceinline__ unsigned long long readlane64(unsigned long long v, int l) {
    unsigned lo = (unsigned)__builtin_amdgcn_readlane((int)(unsigned)v, l);
    unsigned hi = (unsigned)__builtin_amdgcn_readlane((int)(v >> 32), l);
    return ((unsigned long long)hi << 32) | lo;
}

// IoU suppression decision, bit-matching reference op order (a1 = selector area).
__device__ __forceinline__ bool iou_sup(float ay0, float ax0, float ay1, float ax1, float a1,
                                        float by0, float bx0, float by1, float bx1, float a2) {
    float y1 = fmaxf(ay0, by0), x1 = fmaxf(ax0, bx0);
    float y2 = fminf(ay1, by1), x2 = fminf(ax1, bx1);
    float inter = fmaxf(y2 - y1, 0.f) * fmaxf(x2 - x1, 0.f);
    float denom = ((a1 + a2) - inter) + 1e-9f;
    float p = 0.45f * denom;
    float diff = inter - p;
    if (__builtin_fabsf(diff) <= 2e-6f * p) return (inter / denom) > 0.45f; // knife-edge: exact div
    return diff > 0.f;
}

// position of r-th set bit of m (r in [0, popc))
__device__ __forceinline__ int nth_set(unsigned long long m, int r) {
    int src = 0, c;
    c = __popc((unsigned)m);
    if (r >= c) { src = 32; r -= c; m >>= 32; }
    unsigned mm = (unsigned)m;
    c = __popc(mm & 0xFFFFu); if (r >= c) { src += 16; r -= c; mm >>= 16; }
    c = __popc(mm & 0xFFu);   if (r >= c) { src += 8;  r -= c; mm >>= 8; }
    c = __popc(mm & 0xFu);    if (r >= c) { src += 4;  r -= c; mm >>= 4; }
    c = __popc(mm & 0x3u);    if (r >= c) { src += 2;  r -= c; mm >>= 2; }
    c = __popc(mm & 0x1u);    if (r >= c) { src += 1; }
    return src;
}

// Rank-sort `count` unique keys in buf (descending), in place. One wave.
template <int NR>
__device__ __forceinline__ void sort_buf(unsigned long long* buf, int count, int lane) {
    unsigned long long lk[NR];
    int rk[NR];
#pragma unroll
    for (int r = 0; r < NR; ++r) {
        int slot = r * 64 + lane;
        lk[r] = (slot < count) ? buf[slot] : 0ull;
        rk[r] = 0;
    }
    __builtin_amdgcn_wave_barrier();
    for (int j = 0; j < count; ++j) {
        unsigned long long kj = buf[j]; // broadcast read, conflict-free
#pragma unroll
        for (int r = 0; r < NR; ++r) rk[r] += (lk[r] < kj) ? 1 : 0;
    }
    __builtin_amdgcn_wave_barrier();
#pragma unroll
    for (int r = 0; r < NR; ++r) {
        int slot = r * 64 + lane;
        if (slot < count) buf[rk[r]] = lk[r];
    }
    __builtin_amdgcn_wave_barrier();
}

// ---------------- Kernel Z: zero the per-class counters ----------------
__global__ __launch_bounds__(256) void zero_kernel(int* __restrict__ cnt) {
    int i = blockIdx.x * 256 + threadIdx.x;
    if (i < B_IMG * C_CLS) cnt[i] = 0;
}

// ---------------- Kernel A: fused decode + tier-1 filter/scatter ----------------
__global__ __launch_bounds__(256) void fused_decode_filter(const float4* __restrict__ xywh,
                                                           const float4* __restrict__ s4,
                                                           float4* __restrict__ obox,
                                                           unsigned long long* __restrict__ keys1,
                                                           int* __restrict__ cnt1) {
    const int tid = blockIdx.x * 256 + threadIdx.x; // 524288 threads
    if (tid < B_IMG * N_BOX) {
        float4 v = xywh[tid]; // x, y, w, h
        float hh = v.w * 0.5f, hw = v.z * 0.5f;
        float4 o;
        o.x = (v.y - hh) * (1.0f / 256.0f);
        o.y = (v.x - hw) * (1.0f / 256.0f);
        o.z = (v.y + hh) * (1.0f / 256.0f);
        o.w = (v.x + hw) * (1.0f / 256.0f);
        obox[tid] = o;
    }
    const int TOT4 = (B_IMG * N_BOX * C_CLS) / 4; // 5,160,960
#pragma unroll
    for (int k = 0; k < 10; ++k) {
        int f = tid + k * 524288;
        if (f < TOT4) {
            float4 v = s4[f];
            if (v.x >= T1 || v.y >= T1 || v.z >= T1 || v.w >= T1) {
                int box = f / 20;           // (f*4)/80
                int c0 = (f - box * 20) * 4;
                int b = box / N_BOX;
                int n = box - b * N_BOX;
                int lbase = b * C_CLS + c0;
                float ss[4] = {v.x, v.y, v.z, v.w};
#pragma unroll
                for (int e = 0; e < 4; ++e) {
                    if (ss[e] >= T1) {
                        int pos = atomicAdd(&cnt1[lbase + e], 1);
                        if (pos < CAP1)
                            keys1[(size_t)(lbase + e) * CAP1 + pos] =
                                ((unsigned long long)__float_as_uint(ss[e]) << 32) |
                                (unsigned)(~(unsigned)n);
                    }
                }
            }
        }
    }
}

// ---------------- Kernel B: per-class NMS, one wave per (b,c) ----------------
__global__ __launch_bounds__(256) void nms_kernel(const unsigned long long* __restrict__ keys1,
                                                  const int* __restrict__ cnt1,
                                                  const float* __restrict__ scores,
                                                  const float4* __restrict__ boxes,
                                                  float* __restrict__ cls_score,
                                                  int* __restrict__ cls_idx) {
    __shared__ unsigned long long buf_lds[4][FCAP];
    const int w = threadIdx.x >> 6, lane = threadIdx.x & 63;
    const int cl = blockIdx.x * 4 + w; // b*80 + c
    const int b = cl / C_CLS;
    const int c = cl - b * C_CLS;
    unsigned long long* buf = buf_lds[w];
    const float4* bb = boxes + (size_t)b * N_BOX;
    const unsigned long long lmlt = (1ull << lane) - 1ull;

    float sy0 = 0.f, sx0 = 0.f, sy1 = 0.f, sx1 = 0.f, sa = 0.f; // lane i = i-th selection
    float my_score = -1.0f;
    int my_idx = 0;
    int n_sel = 0;

    auto process = [&](int count) {
        int pos = 0;
        while (n_sel < MAX_PER_CLASS && pos < count) {
            int blk = (count - pos < 64) ? count - pos : 64;
            unsigned long long key = (lane < blk) ? buf[pos + lane] : 0ull;
            int ci = (lane < blk) ? (int)(~(unsigned)key) : 0;
            float4 cb = bb[ci];
            if (lane >= blk) cb = make_float4(0.f, 0.f, 0.f, 0.f);
            float ca = fmaxf(cb.z - cb.x, 0.f) * fmaxf(cb.w - cb.y, 0.f);
            // pre-suppression vs already-selected boxes (independent iterations)
            bool psup = false;
            for (int i = 0; i < n_sel; ++i) {
                float by0 = bcastf(sy0, i), bx0 = bcastf(sx0, i);
                float by1 = bcastf(sy1, i), bx1 = bcastf(sx1, i), ba = bcastf(sa, i);
                psup |= iou_sup(by0, bx0, by1, bx1, ba, cb.x, cb.y, cb.z, cb.w, ca);
            }
            unsigned long long supm = __ballot(psup);
            if (blk < 64) supm |= (~0ull) << blk;
            // pairwise suppression masks (independent iterations -> full ILP)
            unsigned long long mjreg = 0ull;
            for (int j = 0; j < blk; ++j) {
                float jy0 = bcastf(cb.x, j), jx0 = bcastf(cb.y, j);
                float jy1 = bcastf(cb.z, j), jx1 = bcastf(cb.w, j), ja = bcastf(ca, j);
                bool sup = iou_sup(jy0, jx0, jy1, jx1, ja, cb.x, cb.y, cb.z, cb.w, ca);
                unsigned long long mj = __ballot(sup);
                if (lane == j) mjreg = mj;
            }
            // scalar greedy closure (reference selection order)
            unsigned long long selm = 0ull;
            int room = MAX_PER_CLASS - n_sel, taken = 0;
            for (int j = 0; j < blk; ++j) {
                if (!((supm >> j) & 1ull)) {
                    selm |= 1ull << j;
                    supm |= readlane64(mjreg, j);
                    if (++taken == room) break;
                }
            }
            // append selected candidates to lanes [n_sel, n_sel+taken)
            int r = lane - n_sel;
            bool recv = (r >= 0) && (r < taken);
            int src = recv ? nth_set(selm, r) : 0;
            float ny0 = __shfl(cb.x, src), nx0 = __shfl(cb.y, src);
            float ny1 = __shfl(cb.z, src), nx1 = __shfl(cb.w, src);
            float na = __shfl(ca, src);
            int nsc = __shfl((int)(key >> 32), src);
            int nid = __shfl((int)(unsigned)key, src);
            if (recv) {
                sy0 = ny0; sx0 = nx0; sy1 = ny1; sx1 = nx1; sa = na;
                my_score = __uint_as_float((unsigned)nsc);
                my_idx = (int)(~(unsigned)nid);
            }
            n_sel += taken;
            pos += blk;
        }
    };

    // tier 1: prebuilt list (unsorted; rank-sort makes order deterministic)
    {
        int count = cnt1[cl];
        if (count > CAP1) count = CAP1;
        const unsigned long long* g = keys1 + (size_t)cl * CAP1;
#pragma unroll
        for (int r2 = 0; r2 < 3; ++r2) {
            int slot = r2 * 64 + lane;
            if (slot < count) buf[slot] = g[slot];
        }
        if (count > 0) {
            sort_buf<3>(buf, count, lane);
            process(count);
        }
    }
    // fallback tiers [0.4, T1): strided collect from original layout (rare)
    for (int t = 0; t < 5 && n_sel < MAX_PER_CLASS; ++t) {
        float lo = d_flo[t];
        float hi = (t == 0) ? T1 : d_flo[t - 1];
        const float* sp = scores + ((size_t)b * N_BOX) * C_CLS + c;
        int cnt = 0;
        for (int ch = 0; ch < N_BOX / 64; ++ch) {
            int n = ch * 64 + lane;
            float s = sp[(size_t)n * C_CLS];
            bool in = (s >= lo) && (s < hi);
            unsigned long long m = __ballot(in);
            if (in) {
                int p = cnt + (int)__popcll(m & lmlt);
                if (p < FCAP)
                    buf[p] = ((unsigned long long)__float_as_uint(s) << 32) |
                             (unsigned)(~(unsigned)n);
            }
            cnt += (int)__popcll(m);
        }
        if (cnt > FCAP) cnt = FCAP;
        if (cnt > 0) {
            sort_buf<8>(buf, cnt, lane);
            process(cnt);
        }
    }

    if (lane < MAX_PER_CLASS) {
        size_t base = (size_t)cl * MAX_PER_CLASS + lane;
        cls_score[base] = my_score; // lanes >= n_sel keep -1 (invalid)
        cls_idx[base] = my_idx;
    }
}

// ---------------- Kernel C: per-image top-50 merge + outputs ----------------
__global__ __launch_bounds__(256) void finalize_kernel(const float* __restrict__ cls_score,
                                                       const int* __restrict__ cls_idx,
                                                       const float4* __restrict__ boxes,
                                                       float* __restrict__ out) {
    const int b = blockIdx.x, t = threadIdx.x;
    const int lane = t & 63, wid = t >> 6;
    __shared__ unsigned long long wtop[4 * MAX_TOTAL];
    __shared__ unsigned long long res[MAX_TOTAL];
    unsigned long long k[16];
    const float* cs = cls_score + (size_t)b * (C_CLS * MAX_PER_CLASS);
#pragma unroll
    for (int j = 0; j < 16; ++j) {
        int flat = j * 256 + t;
        float s = (flat < C_CLS * MAX_PER_CLASS) ? cs[flat] : -1.0f;
        k[j] = (s > 0.0f) ? (((unsigned long long)__float_as_uint(s) << 32) |
                             (unsigned)(~(unsigned)flat))
                          : 0ull;
    }
    for (int iter = 0; iter < MAX_TOTAL; ++iter) {
        unsigned long long m = 0ull;
#pragma unroll
        for (int j = 0; j < 16; ++j)
            if (k[j] > m) m = k[j];
#pragma unroll
        for (int off = 32; off; off >>= 1) {
            unsigned long long o = __shfl_xor(m, off);
            if (o > m) m = o;
        }
        if (m == 0ull) {
            for (int r2 = iter + lane; r2 < MAX_TOTAL; r2 += 64) wtop[wid * MAX_TOTAL + r2] = 0ull;
            break;
        }
        if (lane == 0) wtop[wid * MAX_TOTAL + iter] = m;
#pragma unroll
        for (int j = 0; j < 16; ++j)
            if (k[j] == m) k[j] = 0ull;
    }
    __syncthreads();
    if (wid == 0) {
        if (lane < MAX_TOTAL) res[lane] = 0ull;
        unsigned long long lk[4];
        int rk[4];
#pragma unroll
        for (int r = 0; r < 4; ++r) {
            int slot = r * 64 + lane;
            lk[r] = (slot < 4 * MAX_TOTAL) ? wtop[slot] : 0ull;
            rk[r] = 0;
        }
        for (int j = 0; j < 4 * MAX_TOTAL; ++j) {
            unsigned long long kj = wtop[j];
#pragma unroll
            for (int r = 0; r < 4; ++r) rk[r] += (lk[r] < kj) ? 1 : 0;
        }
        __builtin_amdgcn_wave_barrier();
#pragma unroll
        for (int r = 0; r < 4; ++r)
            if (lk[r] != 0ull && rk[r] < MAX_TOTAL) res[rk[r]] = lk[r];
    }
    if (t < 64) {
        unsigned long long key = (t < MAX_TOTAL) ? res[t] : 0ull;
        bool valid = key != 0ull;
        float s = __uint_as_float((unsigned)(key >> 32));
        unsigned flat = ~(unsigned)key;
        int c = valid ? (int)(flat / 50u) : 0;
        int bidx = valid ? cls_idx[(size_t)b * (C_CLS * MAX_PER_CLASS) + flat] : 0;
        float4 bx = boxes[(size_t)b * N_BOX + bidx];
        float o0 = fminf(fmaxf(bx.x, 0.f), 1.f);
        float o1 = fminf(fmaxf(bx.y, 0.f), 1.f);
        float o2 = fminf(fmaxf(bx.z, 0.f), 1.f);
        float o3 = fminf(fmaxf(bx.w, 0.f), 1.f);
        if (t < MAX_TOTAL) {
            float* ob = out + ((size_t)b * MAX_TOTAL + t) * 4;
            ob[0] = valid ? o0 : 0.f;
            ob[1] = valid ? o1 : 0.f;
            ob[2] = valid ? o2 : 0.f;
            ob[3] = valid ? o3 : 0.f;
            out[B_IMG * MAX_TOTAL * 4 + b * MAX_TOTAL + t] = valid ? s : 0.f;
            out[B_IMG * MAX_TOTAL * 5 + b * MAX_TOTAL + t] = valid ? (float)c : 0.f;
        }
        unsigned long long vb = __ballot(valid);
        if (t == 0) out[B_IMG * MAX_TOTAL * 6 + b] = (float)__popcll(vb);
    }
}

extern "C" void kernel_launch(void* const* d_in, const int* in_sizes, int n_in,
                              void* d_out, int out_size, void* d_ws, size_t ws_size,
                              hipStream_t stream) {
    const float* xywh = (const float*)d_in[0];   // (64,4032,4) f32
    const float* scores = (const float*)d_in[1]; // (64,4032,80) f32
    float* out = (float*)d_out;
    char* ws = (char*)d_ws;

    // ws layout: boxes_dec | keys1 | cnt1 | cls_score | cls_idx  (~14 MB)
    float4* boxes_dec = (float4*)ws;
    size_t off = (size_t)B_IMG * N_BOX * 4 * sizeof(float); // 4,128,768
    unsigned long long* keys1 = (unsigned long long*)(ws + off);
    off += (size_t)B_IMG * C_CLS * CAP1 * 8;                // +7,864,320
    int* cnt1 = (int*)(ws + off);
    off += (size_t)B_IMG * C_CLS * sizeof(int);             // +20,480
    float* cls_score = (float*)(ws + off);
    off += (size_t)B_IMG * C_CLS * MAX_PER_CLASS * sizeof(float);
    int* cls_idx = (int*)(ws + off);

    zero_kernel<<<(B_IMG * C_CLS + 255) / 256, 256, 0, stream>>>(cnt1);
    fused_decode_filter<<<2048, 256, 0, stream>>>((const float4*)xywh, (const float4*)scores,
                                                  boxes_dec, keys1, cnt1);
    nms_kernel<<<(B_IMG * C_CLS) / 4, 256, 0, stream>>>(keys1, cnt1, scores, boxes_dec,
                                                        cls_score, cls_idx);
    finalize_kernel<<<B_IMG, 256, 0, stream>>>(cls_score, cls_idx, boxes_dec, out);
}

// Round 5
// 257.439 us; speedup vs baseline: 1.0693x; 1.0693x over previous
//
#include <hip/hip_runtime.h>
#include <cstdint>
#include <cstddef>

#pragma clang fp contract(off)

#define B_IMG 64
#define N_BOX 4032
#define C_CLS 80
#define MAX_PER_CLASS 50
#define MAX_TOTAL 50
#define SEG 4
#define CAPS 96
#define FCAP 512
#define T1 0.9216f

// Fallback tier bounds: tier t covers [d_flo[t], d_flo[t-1]) (t=0 hi=+inf). Exact tiling of [0.4, inf).
__device__ __constant__ float d_flo[6] = {T1, 0.81f, 0.6724f, 0.5476f, 0.4356f, 0.4f};

__device__ __forceinline__ float bcastf(float v, int l) {
    return __uint_as_float((unsigned)__builtin_amdgcn_readlane((int)__float_as_uint(v), l));
}
__device__ __forceinline__ unsigned long long readlane64(unsigned long long v, int l) {
    unsigned lo = (unsigned)__builtin_amdgcn_readlane((int)(unsigned)v, l);
    unsigned hi = (unsigned)__builtin_amdgcn_readlane((int)(v >> 32), l);
    return ((unsigned long long)hi << 32) | lo;
}

// IoU suppression decision, bit-matching reference op order (a1 = selector area).
__device__ __forceinline__ bool iou_sup(float ay0, float ax0, float ay1, float ax1, float a1,
                                        float by0, float bx0, float by1, float bx1, float a2) {
    float y1 = fmaxf(ay0, by0), x1 = fmaxf(ax0, bx0);
    float y2 = fminf(ay1, by1), x2 = fminf(ax1, bx1);
    float inter = fmaxf(y2 - y1, 0.f) * fmaxf(x2 - x1, 0.f);
    float denom = ((a1 + a2) - inter) + 1e-9f;
    float p = 0.45f * denom;
    float diff = inter - p;
    if (__builtin_fabsf(diff) <= 2e-6f * p) return (inter / denom) > 0.45f; // knife-edge: exact div
    return diff > 0.f;
}

// position of r-th set bit of m (r in [0, popc))
__device__ __forceinline__ int nth_set(unsigned long long m, int r) {
    int src = 0, c;
    c = __popc((unsigned)m);
    if (r >= c) { src = 32; r -= c; m >>= 32; }
    unsigned mm = (unsigned)m;
    c = __popc(mm & 0xFFFFu); if (r >= c) { src += 16; r -= c; mm >>= 16; }
    c = __popc(mm & 0xFFu);   if (r >= c) { src += 8;  r -= c; mm >>= 8; }
    c = __popc(mm & 0xFu);    if (r >= c) { src += 4;  r -= c; mm >>= 4; }
    c = __popc(mm & 0x3u);    if (r >= c) { src += 2;  r -= c; mm >>= 2; }
    c = __popc(mm & 0x1u);    if (r >= c) { src += 1; }
    return src;
}

// Rank-sort `count` unique keys in buf (descending), in place. One wave.
template <int NR>
__device__ __forceinline__ void sort_buf(unsigned long long* buf, int count, int lane) {
    unsigned long long lk[NR];
    int rk[NR];
#pragma unroll
    for (int r = 0; r < NR; ++r) {
        int slot = r * 64 + lane;
        lk[r] = (slot < count) ? buf[slot] : 0ull;
        rk[r] = 0;
    }
    __builtin_amdgcn_wave_barrier();
    for (int j = 0; j < count; ++j) {
        unsigned long long kj = buf[j]; // broadcast read, conflict-free
#pragma unroll
        for (int r = 0; r < NR; ++r) rk[r] += (lk[r] < kj) ? 1 : 0;
    }
    __builtin_amdgcn_wave_barrier();
#pragma unroll
    for (int r = 0; r < NR; ++r) {
        int slot = r * 64 + lane;
        if (slot < count) buf[rk[r]] = lk[r];
    }
    __builtin_amdgcn_wave_barrier();
}

// ---------------- Kernel A: fused decode + tier-1 filter/scatter ----------------
// Counters padded to one per 64B line; lists split 4 ways to cut same-address atomic depth.
__global__ __launch_bounds__(256) void fused_decode_filter(const float4* __restrict__ xywh,
                                                           const float4* __restrict__ s4,
                                                           float4* __restrict__ obox,
                                                           unsigned long long* __restrict__ keys1,
                                                           int* __restrict__ cnt1) {
    const int tid = blockIdx.x * 256 + threadIdx.x; // 524288 threads
    if (tid < B_IMG * N_BOX) {
        float4 v = xywh[tid]; // x, y, w, h
        float hh = v.w * 0.5f, hw = v.z * 0.5f;
        float4 o;
        o.x = (v.y - hh) * (1.0f / 256.0f);
        o.y = (v.x - hw) * (1.0f / 256.0f);
        o.z = (v.y + hh) * (1.0f / 256.0f);
        o.w = (v.x + hw) * (1.0f / 256.0f);
        obox[tid] = o;
    }
    const int TOT4 = (B_IMG * N_BOX * C_CLS) / 4; // 5,160,960
    float4 vv[10];
#pragma unroll
    for (int k = 0; k < 10; ++k) { // batch-issue all loads before any atomic
        int f = tid + k * 524288;
        vv[k] = s4[f < TOT4 ? f : 0];
    }
    const int seg = ((blockIdx.x << 2) + (threadIdx.x >> 6)) & (SEG - 1);
#pragma unroll
    for (int k = 0; k < 10; ++k) {
        int f = tid + k * 524288;
        float4 v = vv[k];
        float m4 = fmaxf(fmaxf(v.x, v.y), fmaxf(v.z, v.w));
        if (f < TOT4 && m4 >= T1) {
            int box = f / 20; // (f*4)/80
            int c0 = (f - box * 20) * 4;
            int b = box / N_BOX;
            int n = box - b * N_BOX;
            int lbase = b * C_CLS + c0;
            float ss[4] = {v.x, v.y, v.z, v.w};
#pragma unroll
            for (int e = 0; e < 4; ++e) {
                if (ss[e] >= T1) {
                    int cl = lbase + e;
                    int pos = atomicAdd(&cnt1[(cl * SEG + seg) * 16], 1);
                    if (pos < CAPS)
                        keys1[((size_t)cl * SEG + seg) * CAPS + pos] =
                            ((unsigned long long)__float_as_uint(ss[e]) << 32) |
                            (unsigned)(~(unsigned)n);
                }
            }
        }
    }
}

// ---------------- Kernel B: per-class NMS, one wave per (b,c) ----------------
__global__ __launch_bounds__(256) void nms_kernel(const unsigned long long* __restrict__ keys1,
                                                  const int* __restrict__ cnt1,
                                                  const float* __restrict__ scores,
                                                  const float4* __restrict__ boxes,
                                                  float* __restrict__ cls_score,
                                                  int* __restrict__ cls_idx) {
    __shared__ unsigned long long buf_lds[4][FCAP];
    const int w = threadIdx.x >> 6, lane = threadIdx.x & 63;
    const int cl = blockIdx.x * 4 + w; // b*80 + c
    const int b = cl / C_CLS;
    const int c = cl - b * C_CLS;
    unsigned long long* buf = buf_lds[w];
    const float4* bb = boxes + (size_t)b * N_BOX;
    const unsigned long long lmlt = (1ull << lane) - 1ull;

    float sy0 = 0.f, sx0 = 0.f, sy1 = 0.f, sx1 = 0.f, sa = 0.f; // lane i = i-th selection
    float my_score = -1.0f;
    int my_idx = 0;
    int n_sel = 0;

    auto process = [&](int count) {
        int pos = 0;
        while (n_sel < MAX_PER_CLASS && pos < count) {
            int blk = (count - pos < 64) ? count - pos : 64;
            unsigned long long key = (lane < blk) ? buf[pos + lane] : 0ull;
            int ci = (lane < blk) ? (int)(~(unsigned)key) : 0;
            float4 cb = bb[ci];
            if (lane >= blk) cb = make_float4(0.f, 0.f, 0.f, 0.f);
            float ca = fmaxf(cb.z - cb.x, 0.f) * fmaxf(cb.w - cb.y, 0.f);
            // pre-suppression vs already-selected boxes (independent iterations)
            bool psup = false;
            for (int i = 0; i < n_sel; ++i) {
                float by0 = bcastf(sy0, i), bx0 = bcastf(sx0, i);
                float by1 = bcastf(sy1, i), bx1 = bcastf(sx1, i), ba = bcastf(sa, i);
                psup |= iou_sup(by0, bx0, by1, bx1, ba, cb.x, cb.y, cb.z, cb.w, ca);
            }
            unsigned long long supm = __ballot(psup);
            if (blk < 64) supm |= (~0ull) << blk;
            // pairwise suppression masks (independent iterations -> full ILP)
            unsigned long long mjreg = 0ull;
            for (int j = 0; j < blk; ++j) {
                float jy0 = bcastf(cb.x, j), jx0 = bcastf(cb.y, j);
                float jy1 = bcastf(cb.z, j), jx1 = bcastf(cb.w, j), ja = bcastf(ca, j);
                bool sup = iou_sup(jy0, jx0, jy1, jx1, ja, cb.x, cb.y, cb.z, cb.w, ca);
                unsigned long long mj = __ballot(sup);
                if (lane == j) mjreg = mj;
            }
            // scalar greedy closure (reference selection order)
            unsigned long long selm = 0ull;
            int room = MAX_PER_CLASS - n_sel, taken = 0;
            for (int j = 0; j < blk; ++j) {
                if (!((supm >> j) & 1ull)) {
                    selm |= 1ull << j;
                    supm |= readlane64(mjreg, j);
                    if (++taken == room) break;
                }
            }
            // append selected candidates to lanes [n_sel, n_sel+taken)
            int r = lane - n_sel;
            bool recv = (r >= 0) && (r < taken);
            int src = recv ? nth_set(selm, r) : 0;
            float ny0 = __shfl(cb.x, src), nx0 = __shfl(cb.y, src);
            float ny1 = __shfl(cb.z, src), nx1 = __shfl(cb.w, src);
            float na = __shfl(ca, src);
            int nsc = __shfl((int)(key >> 32), src);
            int nid = __shfl((int)(unsigned)key, src);
            if (recv) {
                sy0 = ny0; sx0 = nx0; sy1 = ny1; sx1 = nx1; sa = na;
                my_score = __uint_as_float((unsigned)nsc);
                my_idx = (int)(~(unsigned)nid);
            }
            n_sel += taken;
            pos += blk;
        }
    };

    // tier 1: prebuilt segmented lists (unsorted; rank-sort makes order deterministic)
    bool dirty = false;
    {
        int cnts[SEG];
#pragma unroll
        for (int s = 0; s < SEG; ++s) {
            cnts[s] = cnt1[(cl * SEG + s) * 16];
            dirty |= (cnts[s] > CAPS);
        }
        if (!dirty) {
            int base = 0;
#pragma unroll
            for (int s = 0; s < SEG; ++s) {
                const unsigned long long* g = keys1 + ((size_t)cl * SEG + s) * CAPS;
                int cs = cnts[s];
                if (lane < cs) buf[base + lane] = g[lane];
                if (lane + 64 < cs) buf[base + lane + 64] = g[lane + 64];
                base += cs;
            }
            if (base > 0) {
                if (base <= 256) sort_buf<4>(buf, base, lane);
                else             sort_buf<6>(buf, base, lane);
                process(base);
            }
        }
    }
    // fallback tiers: dirty -> from [T1, inf); else [0.4, T1) in 5 exact sub-tiers (rare)
    for (int t = dirty ? 0 : 1; t < 6 && n_sel < MAX_PER_CLASS; ++t) {
        float lo = d_flo[t];
        float hi = (t == 0) ? 3.0e38f : d_flo[t - 1];
        const float* sp = scores + ((size_t)b * N_BOX) * C_CLS + c;
        int cnt = 0;
        for (int ch = 0; ch < N_BOX / 64; ++ch) {
            int n = ch * 64 + lane;
            float s = sp[(size_t)n * C_CLS];
            bool in = (s >= lo) && (s < hi);
            unsigned long long m = __ballot(in);
            if (in) {
                int p = cnt + (int)__popcll(m & lmlt);
                if (p < FCAP)
                    buf[p] = ((unsigned long long)__float_as_uint(s) << 32) |
                             (unsigned)(~(unsigned)n);
            }
            cnt += (int)__popcll(m);
        }
        if (cnt > FCAP) cnt = FCAP;
        if (cnt > 0) {
            sort_buf<8>(buf, cnt, lane);
            process(cnt);
        }
    }

    if (lane < MAX_PER_CLASS) {
        size_t base = (size_t)cl * MAX_PER_CLASS + lane;
        cls_score[base] = my_score; // lanes >= n_sel keep -1 (invalid)
        cls_idx[base] = my_idx;
    }
}

// ---------------- Kernel C: per-image top-50 merge + outputs ----------------
__global__ __launch_bounds__(256) void finalize_kernel(const float* __restrict__ cls_score,
                                                       const int* __restrict__ cls_idx,
                                                       const float4* __restrict__ boxes,
                                                       float* __restrict__ out) {
    const int b = blockIdx.x, t = threadIdx.x;
    const int lane = t & 63, wid = t >> 6;
    __shared__ unsigned long long wtop[4 * MAX_TOTAL];
    __shared__ unsigned long long res[MAX_TOTAL];
    unsigned long long k[16];
    const float* cs = cls_score + (size_t)b * (C_CLS * MAX_PER_CLASS);
#pragma unroll
    for (int j = 0; j < 16; ++j) {
        int flat = j * 256 + t;
        float s = (flat < C_CLS * MAX_PER_CLASS) ? cs[flat] : -1.0f;
        k[j] = (s > 0.0f) ? (((unsigned long long)__float_as_uint(s) << 32) |
                             (unsigned)(~(unsigned)flat))
                          : 0ull;
    }
    for (int iter = 0; iter < MAX_TOTAL; ++iter) {
        unsigned long long m = 0ull;
#pragma unroll
        for (int j = 0; j < 16; ++j)
            if (k[j] > m) m = k[j];
#pragma unroll
        for (int off = 32; off; off >>= 1) {
            unsigned long long o = __shfl_xor(m, off);
            if (o > m) m = o;
        }
        if (m == 0ull) {
            for (int r2 = iter + lane; r2 < MAX_TOTAL; r2 += 64) wtop[wid * MAX_TOTAL + r2] = 0ull;
            break;
        }
        if (lane == 0) wtop[wid * MAX_TOTAL + iter] = m;
#pragma unroll
        for (int j = 0; j < 16; ++j)
            if (k[j] == m) k[j] = 0ull;
    }
    __syncthreads();
    if (wid == 0) {
        if (lane < MAX_TOTAL) res[lane] = 0ull;
        unsigned long long lk[4];
        int rk[4];
#pragma unroll
        for (int r = 0; r < 4; ++r) {
            int slot = r * 64 + lane;
            lk[r] = (slot < 4 * MAX_TOTAL) ? wtop[slot] : 0ull;
            rk[r] = 0;
        }
        for (int j = 0; j < 4 * MAX_TOTAL; ++j) {
            unsigned long long kj = wtop[j];
#pragma unroll
            for (int r = 0; r < 4; ++r) rk[r] += (lk[r] < kj) ? 1 : 0;
        }
        __builtin_amdgcn_wave_barrier();
#pragma unroll
        for (int r = 0; r < 4; ++r)
            if (lk[r] != 0ull && rk[r] < MAX_TOTAL) res[rk[r]] = lk[r];
    }
    if (t < 64) {
        unsigned long long key = (t < MAX_TOTAL) ? res[t] : 0ull;
        bool valid = key != 0ull;
        float s = __uint_as_float((unsigned)(key >> 32));
        unsigned flat = ~(unsigned)key;
        int c = valid ? (int)(flat / 50u) : 0;
        int bidx = valid ? cls_idx[(size_t)b * (C_CLS * MAX_PER_CLASS) + flat] : 0;
        float4 bx = boxes[(size_t)b * N_BOX + bidx];
        float o0 = fminf(fmaxf(bx.x, 0.f), 1.f);
        float o1 = fminf(fmaxf(bx.y, 0.f), 1.f);
        float o2 = fminf(fmaxf(bx.z, 0.f), 1.f);
        float o3 = fminf(fmaxf(bx.w, 0.f), 1.f);
        if (t < MAX_TOTAL) {
            float* ob = out + ((size_t)b * MAX_TOTAL + t) * 4;
            ob[0] = valid ? o0 : 0.f;
            ob[1] = valid ? o1 : 0.f;
            ob[2] = valid ? o2 : 0.f;
            ob[3] = valid ? o3 : 0.f;
            out[B_IMG * MAX_TOTAL * 4 + b * MAX_TOTAL + t] = valid ? s : 0.f;
            out[B_IMG * MAX_TOTAL * 5 + b * MAX_TOTAL + t] = valid ? (float)c : 0.f;
        }
        unsigned long long vb = __ballot(valid);
        if (t == 0) out[B_IMG * MAX_TOTAL * 6 + b] = (float)__popcll(vb);
    }
}

extern "C" void kernel_launch(void* const* d_in, const int* in_sizes, int n_in,
                              void* d_out, int out_size, void* d_ws, size_t ws_size,
                              hipStream_t stream) {
    const float* xywh = (const float*)d_in[0];   // (64,4032,4) f32
    const float* scores = (const float*)d_in[1]; // (64,4032,80) f32
    float* out = (float*)d_out;
    char* ws = (char*)d_ws;

    // ws layout: boxes_dec | keys1 | cnt1(padded) | cls_score | cls_idx  (~23 MB)
    float4* boxes_dec = (float4*)ws;
    size_t off = (size_t)B_IMG * N_BOX * 4 * sizeof(float);      // 4,128,768
    unsigned long long* keys1 = (unsigned long long*)(ws + off);
    off += (size_t)B_IMG * C_CLS * SEG * CAPS * 8;               // +15,728,640
    int* cnt1 = (int*)(ws + off);
    size_t cntBytes = (size_t)B_IMG * C_CLS * SEG * 64;          // 1,310,720 (64B-padded)
    off += cntBytes;
    float* cls_score = (float*)(ws + off);
    off += (size_t)B_IMG * C_CLS * MAX_PER_CLASS * sizeof(float);
    int* cls_idx = (int*)(ws + off);

    hipMemsetAsync(cnt1, 0, cntBytes, stream);
    fused_decode_filter<<<2048, 256, 0, stream>>>((const float4*)xywh, (const float4*)scores,
                                                  boxes_dec, keys1, cnt1);
    nms_kernel<<<(B_IMG * C_CLS) / 4, 256, 0, stream>>>(keys1, cnt1, scores, boxes_dec,
                                                        cls_score, cls_idx);
    finalize_kernel<<<B_IMG, 256, 0, stream>>>(cls_score, cls_idx, boxes_dec, out);
}

// Round 6
// 223.987 us; speedup vs baseline: 1.2290x; 1.1493x over previous
//
#include <hip/hip_runtime.h>
#include <cstdint>
#include <cstddef>

#pragma clang fp contract(off)

#define B_IMG 64
#define N_BOX 4032
#define C_CLS 80
#define NCH 63          // 4032 / 64 box-chunks
#define MAX_PER_CLASS 50
#define MAX_TOTAL 50
#define FCAP 512
#define T1 0.9216f
#define T2 0.81f

// Fallback tier bounds: tier t covers [d_flo[t], d_flo[t-1]) (t=0 hi=+inf). Exact tiling of [0.4, inf).
// Tier 0 = bitmap1 range, tier 1 = bitmap2 range.
__device__ __constant__ float d_flo[6] = {T1, T2, 0.6724f, 0.5476f, 0.4356f, 0.4f};

__device__ __forceinline__ float bcastf(float v, int l) {
    return __uint_as_float((unsigned)__builtin_amdgcn_readlane((int)__float_as_uint(v), l));
}
__device__ __forceinline__ unsigned long long readlane64(unsigned long long v, int l) {
    unsigned lo = (unsigned)__builtin_amdgcn_readlane((int)(unsigned)v, l);
    unsigned hi = (unsigned)__builtin_amdgcn_readlane((int)(v >> 32), l);
    return ((unsigned long long)hi << 32) | lo;
}

// IoU suppression decision, bit-matching reference op order (a1 = selector area).
__device__ __forceinline__ bool iou_sup(float ay0, float ax0, float ay1, float ax1, float a1,
                                        float by0, float bx0, float by1, float bx1, float a2) {
    float y1 = fmaxf(ay0, by0), x1 = fmaxf(ax0, bx0);
    float y2 = fminf(ay1, by1), x2 = fminf(ax1, bx1);
    float inter = fmaxf(y2 - y1, 0.f) * fmaxf(x2 - x1, 0.f);
    float denom = ((a1 + a2) - inter) + 1e-9f;
    float p = 0.45f * denom;
    float diff = inter - p;
    if (__builtin_fabsf(diff) <= 2e-6f * p) return (inter / denom) > 0.45f; // knife-edge: exact div
    return diff > 0.f;
}

// position of r-th set bit of m (r in [0, popc))
__device__ __forceinline__ int nth_set(unsigned long long m, int r) {
    int src = 0, c;
    c = __popc((unsigned)m);
    if (r >= c) { src = 32; r -= c; m >>= 32; }
    unsigned mm = (unsigned)m;
    c = __popc(mm & 0xFFFFu); if (r >= c) { src += 16; r -= c; mm >>= 16; }
    c = __popc(mm & 0xFFu);   if (r >= c) { src += 8;  r -= c; mm >>= 8; }
    c = __popc(mm & 0xFu);    if (r >= c) { src += 4;  r -= c; mm >>= 4; }
    c = __popc(mm & 0x3u);    if (r >= c) { src += 2;  r -= c; mm >>= 2; }
    c = __popc(mm & 0x1u);    if (r >= c) { src += 1; }
    return src;
}

// Rank-sort `count` unique keys in buf (descending), in place. One wave.
template <int NR>
__device__ __forceinline__ void sort_buf(unsigned long long* buf, int count, int lane) {
    unsigned long long lk[NR];
    int rk[NR];
#pragma unroll
    for (int r = 0; r < NR; ++r) {
        int slot = r * 64 + lane;
        lk[r] = (slot < count) ? buf[slot] : 0ull;
        rk[r] = 0;
    }
    __builtin_amdgcn_wave_barrier();
    for (int j = 0; j < count; ++j) {
        unsigned long long kj = buf[j]; // broadcast read, conflict-free
#pragma unroll
        for (int r = 0; r < NR; ++r) rk[r] += (lk[r] < kj) ? 1 : 0;
    }
    __builtin_amdgcn_wave_barrier();
#pragma unroll
    for (int r = 0; r < NR; ++r) {
        int slot = r * 64 + lane;
        if (slot < count) buf[rk[r]] = lk[r];
    }
    __builtin_amdgcn_wave_barrier();
}

// ---------------- Kernel A: fused decode + dual-threshold ballot bitmaps ----------------
// Wave = (image b, chunk h of 64 boxes). Per class: one ballot -> one bitmap word, written once.
// No atomics, no memset, coalesced stores. bm layout: bm[(b*NCH + h)*C_CLS + c].
__global__ __launch_bounds__(256) void fused_decode_filter(const float4* __restrict__ xywh,
                                                           const float4* __restrict__ s4,
                                                           float4* __restrict__ obox,
                                                           unsigned long long* __restrict__ bm1,
                                                           unsigned long long* __restrict__ bm2) {
    const int tid = blockIdx.x * 256 + threadIdx.x; // 258048 = B*N threads exactly
    const int lane = threadIdx.x & 63;
    {
        float4 v = xywh[tid]; // x, y, w, h
        float hh = v.w * 0.5f, hw = v.z * 0.5f;
        float4 o;
        o.x = (v.y - hh) * (1.0f / 256.0f);
        o.y = (v.x - hw) * (1.0f / 256.0f);
        o.z = (v.y + hh) * (1.0f / 256.0f);
        o.w = (v.x + hw) * (1.0f / 256.0f);
        obox[tid] = o;
    }
    const int g = tid >> 6;           // wave id = b*NCH + h
    const int b = g / NCH, h = g - b * NCH;
    const int n = h * 64 + lane;      // this lane's box
    const float4* row = s4 + (size_t)(b * N_BOX + n) * (C_CLS / 4); // 20 float4 = one box row
    unsigned long long w1a = 0, w2a = 0, w1b = 0, w2b = 0; // class words held per lane
#pragma unroll
    for (int gg = 0; gg < 20; ++gg) {
        float4 v = row[gg]; // one 64B line per lane; 4 classes
        float ss[4] = {v.x, v.y, v.z, v.w};
#pragma unroll
        for (int e = 0; e < 4; ++e) {
            int c = gg * 4 + e;
            bool in1 = ss[e] >= T1;
            bool in2 = (ss[e] >= T2) && !in1;
            unsigned long long m1 = __ballot(in1);
            unsigned long long m2 = __ballot(in2);
            if (c < 64) {
                if (lane == c) { w1a = m1; w2a = m2; }
            } else {
                if (lane == c - 64) { w1b = m1; w2b = m2; }
            }
        }
    }
    size_t base = (size_t)g * C_CLS;
    bm1[base + lane] = w1a; // classes 0..63, coalesced 512B
    bm2[base + lane] = w2a;
    if (lane < 16) {
        bm1[base + 64 + lane] = w1b; // classes 64..79
        bm2[base + 64 + lane] = w2b;
    }
}

// ---------------- Kernel B: per-class NMS, one wave per (b,c) ----------------
__global__ __launch_bounds__(256) void nms_kernel(const unsigned long long* __restrict__ bm1,
                                                  const unsigned long long* __restrict__ bm2,
                                                  const float* __restrict__ scores,
                                                  const float4* __restrict__ boxes,
                                                  float* __restrict__ cls_score,
                                                  int* __restrict__ cls_idx) {
    __shared__ unsigned long long buf_lds[4][FCAP];
    const int w = threadIdx.x >> 6, lane = threadIdx.x & 63;
    const int cl = blockIdx.x * 4 + w; // b*80 + c
    const int b = cl / C_CLS;
    const int c = cl - b * C_CLS;
    unsigned long long* buf = buf_lds[w];
    const float4* bb = boxes + (size_t)b * N_BOX;
    const unsigned long long lmlt = (1ull << lane) - 1ull;

    float sy0 = 0.f, sx0 = 0.f, sy1 = 0.f, sx1 = 0.f, sa = 0.f; // lane i = i-th selection
    float my_score = -1.0f;
    int my_idx = 0;
    int n_sel = 0;

    auto process = [&](int count) {
        int pos = 0;
        while (n_sel < MAX_PER_CLASS && pos < count) {
            int blk = (count - pos < 64) ? count - pos : 64;
            unsigned long long key = (lane < blk) ? buf[pos + lane] : 0ull;
            int ci = (lane < blk) ? (int)(~(unsigned)key) : 0;
            float4 cb = bb[ci];
            if (lane >= blk) cb = make_float4(0.f, 0.f, 0.f, 0.f);
            float ca = fmaxf(cb.z - cb.x, 0.f) * fmaxf(cb.w - cb.y, 0.f);
            // pre-suppression vs already-selected boxes (independent iterations)
            bool psup = false;
            for (int i = 0; i < n_sel; ++i) {
                float by0 = bcastf(sy0, i), bx0 = bcastf(sx0, i);
                float by1 = bcastf(sy1, i), bx1 = bcastf(sx1, i), ba = bcastf(sa, i);
                psup |= iou_sup(by0, bx0, by1, bx1, ba, cb.x, cb.y, cb.z, cb.w, ca);
            }
            unsigned long long supm = __ballot(psup);
            if (blk < 64) supm |= (~0ull) << blk;
            // pairwise suppression masks (independent iterations -> full ILP)
            unsigned long long mjreg = 0ull;
            for (int j = 0; j < blk; ++j) {
                float jy0 = bcastf(cb.x, j), jx0 = bcastf(cb.y, j);
                float jy1 = bcastf(cb.z, j), jx1 = bcastf(cb.w, j), ja = bcastf(ca, j);
                bool sup = iou_sup(jy0, jx0, jy1, jx1, ja, cb.x, cb.y, cb.z, cb.w, ca);
                unsigned long long mj = __ballot(sup);
                if (lane == j) mjreg = mj;
            }
            // scalar greedy closure (reference selection order)
            unsigned long long selm = 0ull;
            int room = MAX_PER_CLASS - n_sel, taken = 0;
            for (int j = 0; j < blk; ++j) {
                if (!((supm >> j) & 1ull)) {
                    selm |= 1ull << j;
                    supm |= readlane64(mjreg, j);
                    if (++taken == room) break;
                }
            }
            // append selected candidates to lanes [n_sel, n_sel+taken)
            int r = lane - n_sel;
            bool recv = (r >= 0) && (r < taken);
            int src = recv ? nth_set(selm, r) : 0;
            float ny0 = __shfl(cb.x, src), nx0 = __shfl(cb.y, src);
            float ny1 = __shfl(cb.z, src), nx1 = __shfl(cb.w, src);
            float na = __shfl(ca, src);
            int nsc = __shfl((int)(key >> 32), src);
            int nid = __shfl((int)(unsigned)key, src);
            if (recv) {
                sy0 = ny0; sx0 = nx0; sy1 = ny1; sx1 = nx1; sa = na;
                my_score = __uint_as_float((unsigned)nsc);
                my_idx = (int)(~(unsigned)nid);
            }
            n_sel += taken;
            pos += blk;
        }
    };

    // Build candidate list from a bitmap: deterministic ascending-n order, then score-gather.
    // Returns count, or -1 on (statistically impossible) overflow.
    auto load_tier = [&](const unsigned long long* bm) -> int {
        unsigned long long wd = 0ull;
        if (lane < NCH) wd = bm[(size_t)(b * NCH + lane) * C_CLS + c];
        int cntl = __popcll(wd);
        int incl = cntl;
#pragma unroll
        for (int off = 1; off < 64; off <<= 1) {
            int v = __shfl_up(incl, off);
            if (lane >= off) incl += v;
        }
        int total = __builtin_amdgcn_readlane(incl, 63);
        if (total > FCAP) return -1;
        int basep = incl - cntl;
        unsigned long long ww = wd;
        int r = 0;
        while (ww) {
            int bit = __ffsll((unsigned long long)ww) - 1;
            ww &= ww - 1;
            buf[basep + r] = (unsigned long long)(unsigned)(lane * 64 + bit);
            ++r;
        }
        __builtin_amdgcn_wave_barrier();
        const float* sp = scores + ((size_t)b * N_BOX) * C_CLS + c;
        for (int i = lane; i < total; i += 64) {
            int n = (int)buf[i];
            float s = sp[(size_t)n * C_CLS]; // scattered, L3-resident
            buf[i] = ((unsigned long long)__float_as_uint(s) << 32) | (unsigned)(~(unsigned)n);
        }
        __builtin_amdgcn_wave_barrier();
        return total;
    };

    int dirtyStart = -1;
    {
        int cnt1 = load_tier(bm1);
        if (cnt1 < 0) dirtyStart = 0;
        else {
            if (cnt1 > 0) {
                if (cnt1 <= 256) sort_buf<4>(buf, cnt1, lane);
                else             sort_buf<8>(buf, cnt1, lane);
                process(cnt1);
            }
            if (n_sel < MAX_PER_CLASS) {
                int cnt2 = load_tier(bm2);
                if (cnt2 < 0) dirtyStart = 1;
                else {
                    if (cnt2 > 0) {
                        if (cnt2 <= 256) sort_buf<4>(buf, cnt2, lane);
                        else             sort_buf<8>(buf, cnt2, lane);
                        process(cnt2);
                    }
                    if (n_sel < MAX_PER_CLASS) dirtyStart = 2; // below T2
                }
            }
        }
    }
    // fallback tiers via strided rescan (statistically never; correctness-required)
    for (int t = (dirtyStart < 0) ? 6 : dirtyStart; t < 6 && n_sel < MAX_PER_CLASS; ++t) {
        float lo = d_flo[t];
        float hi = (t == 0) ? 3.0e38f : d_flo[t - 1];
        const float* sp = scores + ((size_t)b * N_BOX) * C_CLS + c;
        int cnt = 0;
        for (int ch = 0; ch < N_BOX / 64; ++ch) {
            int n = ch * 64 + lane;
            float s = sp[(size_t)n * C_CLS];
            bool in = (s >= lo) && (s < hi);
            unsigned long long m = __ballot(in);
            if (in) {
                int p = cnt + (int)__popcll(m & lmlt);
                if (p < FCAP)
                    buf[p] = ((unsigned long long)__float_as_uint(s) << 32) |
                             (unsigned)(~(unsigned)n);
            }
            cnt += (int)__popcll(m);
        }
        if (cnt > FCAP) cnt = FCAP;
        if (cnt > 0) {
            sort_buf<8>(buf, cnt, lane);
            process(cnt);
        }
    }

    if (lane < MAX_PER_CLASS) {
        size_t base = (size_t)cl * MAX_PER_CLASS + lane;
        cls_score[base] = my_score; // lanes >= n_sel keep -1 (invalid)
        cls_idx[base] = my_idx;
    }
}

// ---------------- Kernel C: per-image top-50 merge + outputs ----------------
__global__ __launch_bounds__(256) void finalize_kernel(const float* __restrict__ cls_score,
                                                       const int* __restrict__ cls_idx,
                                                       const float4* __restrict__ boxes,
                                                       float* __restrict__ out) {
    const int b = blockIdx.x, t = threadIdx.x;
    const int lane = t & 63, wid = t >> 6;
    __shared__ unsigned long long wtop[4 * MAX_TOTAL];
    __shared__ unsigned long long res[MAX_TOTAL];
    unsigned long long k[16];
    const float* cs = cls_score + (size_t)b * (C_CLS * MAX_PER_CLASS);
#pragma unroll
    for (int j = 0; j < 16; ++j) {
        int flat = j * 256 + t;
        float s = (flat < C_CLS * MAX_PER_CLASS) ? cs[flat] : -1.0f;
        k[j] = (s > 0.0f) ? (((unsigned long long)__float_as_uint(s) << 32) |
                             (unsigned)(~(unsigned)flat))
                          : 0ull;
    }
    for (int iter = 0; iter < MAX_TOTAL; ++iter) {
        unsigned long long m = 0ull;
#pragma unroll
        for (int j = 0; j < 16; ++j)
            if (k[j] > m) m = k[j];
#pragma unroll
        for (int off = 32; off; off >>= 1) {
            unsigned long long o = __shfl_xor(m, off);
            if (o > m) m = o;
        }
        if (m == 0ull) {
            for (int r2 = iter + lane; r2 < MAX_TOTAL; r2 += 64) wtop[wid * MAX_TOTAL + r2] = 0ull;
            break;
        }
        if (lane == 0) wtop[wid * MAX_TOTAL + iter] = m;
#pragma unroll
        for (int j = 0; j < 16; ++j)
            if (k[j] == m) k[j] = 0ull;
    }
    __syncthreads();
    if (wid == 0) {
        if (lane < MAX_TOTAL) res[lane] = 0ull;
        unsigned long long lk[4];
        int rk[4];
#pragma unroll
        for (int r = 0; r < 4; ++r) {
            int slot = r * 64 + lane;
            lk[r] = (slot < 4 * MAX_TOTAL) ? wtop[slot] : 0ull;
            rk[r] = 0;
        }
        for (int j = 0; j < 4 * MAX_TOTAL; ++j) {
            unsigned long long kj = wtop[j];
#pragma unroll
            for (int r = 0; r < 4; ++r) rk[r] += (lk[r] < kj) ? 1 : 0;
        }
        __builtin_amdgcn_wave_barrier();
#pragma unroll
        for (int r = 0; r < 4; ++r)
            if (lk[r] != 0ull && rk[r] < MAX_TOTAL) res[rk[r]] = lk[r];
    }
    if (t < 64) {
        unsigned long long key = (t < MAX_TOTAL) ? res[t] : 0ull;
        bool valid = key != 0ull;
        float s = __uint_as_float((unsigned)(key >> 32));
        unsigned flat = ~(unsigned)key;
        int c = valid ? (int)(flat / 50u) : 0;
        int bidx = valid ? cls_idx[(size_t)b * (C_CLS * MAX_PER_CLASS) + flat] : 0;
        float4 bx = boxes[(size_t)b * N_BOX + bidx];
        float o0 = fminf(fmaxf(bx.x, 0.f), 1.f);
        float o1 = fminf(fmaxf(bx.y, 0.f), 1.f);
        float o2 = fminf(fmaxf(bx.z, 0.f), 1.f);
        float o3 = fminf(fmaxf(bx.w, 0.f), 1.f);
        if (t < MAX_TOTAL) {
            float* ob = out + ((size_t)b * MAX_TOTAL + t) * 4;
            ob[0] = valid ? o0 : 0.f;
            ob[1] = valid ? o1 : 0.f;
            ob[2] = valid ? o2 : 0.f;
            ob[3] = valid ? o3 : 0.f;
            out[B_IMG * MAX_TOTAL * 4 + b * MAX_TOTAL + t] = valid ? s : 0.f;
            out[B_IMG * MAX_TOTAL * 5 + b * MAX_TOTAL + t] = valid ? (float)c : 0.f;
        }
        unsigned long long vb = __ballot(valid);
        if (t == 0) out[B_IMG * MAX_TOTAL * 6 + b] = (float)__popcll(vb);
    }
}

extern "C" void kernel_launch(void* const* d_in, const int* in_sizes, int n_in,
                              void* d_out, int out_size, void* d_ws, size_t ws_size,
                              hipStream_t stream) {
    const float* xywh = (const float*)d_in[0];   // (64,4032,4) f32
    const float* scores = (const float*)d_in[1]; // (64,4032,80) f32
    float* out = (float*)d_out;
    char* ws = (char*)d_ws;

    // ws layout: boxes_dec | bm1 | bm2 | cls_score | cls_idx  (~11.3 MB)
    float4* boxes_dec = (float4*)ws;
    size_t off = (size_t)B_IMG * N_BOX * 4 * sizeof(float);       // 4,128,768
    unsigned long long* bm1 = (unsigned long long*)(ws + off);
    off += (size_t)B_IMG * NCH * C_CLS * 8;                       // +2,580,480
    unsigned long long* bm2 = (unsigned long long*)(ws + off);
    off += (size_t)B_IMG * NCH * C_CLS * 8;                       // +2,580,480
    float* cls_score = (float*)(ws + off);
    off += (size_t)B_IMG * C_CLS * MAX_PER_CLASS * sizeof(float);
    int* cls_idx = (int*)(ws + off);

    fused_decode_filter<<<(B_IMG * N_BOX) / 256, 256, 0, stream>>>(
        (const float4*)xywh, (const float4*)scores, boxes_dec, bm1, bm2);
    nms_kernel<<<(B_IMG * C_CLS) / 4, 256, 0, stream>>>(bm1, bm2, scores, boxes_dec,
                                                        cls_score, cls_idx);
    finalize_kernel<<<B_IMG, 256, 0, stream>>>(cls_score, cls_idx, boxes_dec, out);
}

// Round 8
// 199.149 us; speedup vs baseline: 1.3822x; 1.1247x over previous
//
#include <hip/hip_runtime.h>
#include <cstdint>
#include <cstddef>

#pragma clang fp contract(off)

#define B_IMG 64
#define N_BOX 4032
#define C_CLS 80
#define NCH 63          // 4032 / 64 box-chunks
#define MAX_PER_CLASS 50
#define MAX_TOTAL 50
#define FCAP 512
#define T1 0.9559f
#define T2 0.81f

// Fallback tier bounds: tier t covers [d_flo[t], d_flo[t-1]) (t=0 hi=+inf). Exact tiling of [0.4, inf).
// Tier 0 = bitmap1 range, tier 1 = bitmap2 range.
__device__ __constant__ float d_flo[6] = {T1, T2, 0.6724f, 0.5476f, 0.4356f, 0.4f};

__device__ __forceinline__ float bcastf(float v, int l) {
    return __uint_as_float((unsigned)__builtin_amdgcn_readlane((int)__float_as_uint(v), l));
}

// IoU suppression decision, bit-matching reference op order (a1 = selector area).
// Note: exactly symmetric in (box_a, box_b) — fmax/fmin/add commute bitwise.
__device__ __forceinline__ bool iou_sup(float ay0, float ax0, float ay1, float ax1, float a1,
                                        float by0, float bx0, float by1, float bx1, float a2) {
    float y1 = fmaxf(ay0, by0), x1 = fmaxf(ax0, bx0);
    float y2 = fminf(ay1, by1), x2 = fminf(ax1, bx1);
    float inter = fmaxf(y2 - y1, 0.f) * fmaxf(x2 - x1, 0.f);
    float denom = ((a1 + a2) - inter) + 1e-9f;
    float p = 0.45f * denom;
    float diff = inter - p;
    if (__builtin_fabsf(diff) <= 2e-6f * p) return (inter / denom) > 0.45f; // knife-edge: exact div
    return diff > 0.f;
}

// Rank-sort `count` unique keys in buf (descending), in place. One wave.
template <int NR>
__device__ __forceinline__ void sort_buf(unsigned long long* buf, int count, int lane) {
    unsigned long long lk[NR];
    int rk[NR];
#pragma unroll
    for (int r = 0; r < NR; ++r) {
        int slot = r * 64 + lane;
        lk[r] = (slot < count) ? buf[slot] : 0ull;
        rk[r] = 0;
    }
    __builtin_amdgcn_wave_barrier();
    for (int j = 0; j < count; ++j) {
        unsigned long long kj = buf[j]; // broadcast read, conflict-free
#pragma unroll
        for (int r = 0; r < NR; ++r) rk[r] += (lk[r] < kj) ? 1 : 0;
    }
    __builtin_amdgcn_wave_barrier();
#pragma unroll
    for (int r = 0; r < NR; ++r) {
        int slot = r * 64 + lane;
        if (slot < count) buf[rk[r]] = lk[r];
    }
    __builtin_amdgcn_wave_barrier();
}

// ---------------- Kernel A: fused decode + dual-threshold ballot bitmaps ----------------
// Block = (image b, chunk h of 64 boxes): contiguous 20KB score region -> LDS (stride 81,
// gcd(81,32)=1 -> conflict-free column reads) -> per-wave ballots. No atomics, coalesced I/O.
__global__ __launch_bounds__(256) void fused_decode_filter(const float4* __restrict__ xywh,
                                                           const float4* __restrict__ s4,
                                                           float4* __restrict__ obox,
                                                           unsigned long long* __restrict__ bm1,
                                                           unsigned long long* __restrict__ bm2) {
    __shared__ float tile[64 * 81]; // 20736 B
    const int t = threadIdx.x;
    const int g = blockIdx.x; // b*NCH + h
    const int b = g / NCH, h = g - b * NCH;
    const int boxBase = b * N_BOX + h * 64;
    const float4* src = s4 + (size_t)boxBase * 20;
#pragma unroll
    for (int k = 0; k < 5; ++k) {
        int f4 = k * 256 + t;  // 0..1279
        float4 v = src[f4];
        int f = f4 * 4;
        int n = f / 80, c = f - n * 80; // c%4==0, row-aligned (80%4==0)
        float* dst = tile + n * 81 + c;
        dst[0] = v.x; dst[1] = v.y; dst[2] = v.z; dst[3] = v.w;
    }
    if (t < 64) { // decode 64 boxes (coalesced 1KB)
        float4 v = xywh[boxBase + t]; // x, y, w, h
        float hh = v.w * 0.5f, hw = v.z * 0.5f;
        float4 o;
        o.x = (v.y - hh) * (1.0f / 256.0f);
        o.y = (v.x - hw) * (1.0f / 256.0f);
        o.z = (v.y + hh) * (1.0f / 256.0f);
        o.w = (v.x + hw) * (1.0f / 256.0f);
        obox[boxBase + t] = o;
    }
    __syncthreads();
    const int wv = t >> 6, lane = t & 63;
    unsigned long long w1 = 0, w2 = 0;
    const float* col = tile + lane * 81;
#pragma unroll
    for (int cc = 0; cc < 20; ++cc) {
        int c = wv * 20 + cc;
        float s = col[c];
        unsigned long long m1 = __ballot(s >= T1);
        unsigned long long m2 = __ballot((s >= T2) && (s < T1));
        if (lane == cc) { w1 = m1; w2 = m2; }
    }
    size_t base = (size_t)g * C_CLS + wv * 20;
    if (lane < 20) { bm1[base + lane] = w1; bm2[base + lane] = w2; }
}

// ---------------- Kernel B: per-class NMS, one wave per (b,c) ----------------
__global__ __launch_bounds__(256) void nms_kernel(const unsigned long long* __restrict__ bm1,
                                                  const unsigned long long* __restrict__ bm2,
                                                  const float* __restrict__ scores,
                                                  const float4* __restrict__ boxes,
                                                  float* __restrict__ cls_score,
                                                  int* __restrict__ cls_idx) {
    __shared__ unsigned long long buf_lds[4][FCAP];
    const int w = threadIdx.x >> 6, lane = threadIdx.x & 63;
    const int cl = blockIdx.x * 4 + w; // b*80 + c
    const int b = cl / C_CLS;
    const int c = cl - b * C_CLS;
    unsigned long long* buf = buf_lds[w];
    const float4* bb = boxes + (size_t)b * N_BOX;
    const unsigned long long lmlt = (1ull << lane) - 1ull;

    float sy0 = 0.f, sx0 = 0.f, sy1 = 0.f, sx1 = 0.f, sa = 0.f; // lane i = i-th selection
    float my_score = -1.0f;
    int my_idx = 0;
    int n_sel = 0;

    // Process a sorted candidate list: on-demand greedy (mask per SELECTED j only).
    auto process = [&](int count) {
        int pos = 0;
        while (n_sel < MAX_PER_CLASS && pos < count) {
            int blk = (count - pos < 64) ? count - pos : 64;
            unsigned long long key = (lane < blk) ? buf[pos + lane] : 0ull;
            int ci = (lane < blk) ? (int)(~(unsigned)key) : 0;
            float4 cb = bb[ci];
            if (lane >= blk) cb = make_float4(0.f, 0.f, 0.f, 0.f);
            float ca = fmaxf(cb.z - cb.x, 0.f) * fmaxf(cb.w - cb.y, 0.f);
            // pre-suppression vs already-selected boxes (independent iterations)
            bool psup = false;
            for (int i = 0; i < n_sel; ++i) {
                float by0 = bcastf(sy0, i), bx0 = bcastf(sx0, i);
                float by1 = bcastf(sy1, i), bx1 = bcastf(sx1, i), ba = bcastf(sa, i);
                psup |= iou_sup(by0, bx0, by1, bx1, ba, cb.x, cb.y, cb.z, cb.w, ca);
            }
            unsigned long long supm = __ballot(psup); // wave-uniform SGPR
            if (blk < 64) supm |= (~0ull) << blk;
            // greedy walk: first unsuppressed j is selected; one IoU+ballot updates supm.
            while (true) {
                unsigned long long un = ~supm;
                if (un == 0ull) break;
                int j = __ffsll(un) - 1; // uniform
                float jy0 = bcastf(cb.x, j), jx0 = bcastf(cb.y, j);
                float jy1 = bcastf(cb.z, j), jx1 = bcastf(cb.w, j), ja = bcastf(ca, j);
                int jsc = __builtin_amdgcn_readlane((int)(key >> 32), j);
                int jid = __builtin_amdgcn_readlane((int)(unsigned)key, j);
                if (lane == n_sel) {
                    sy0 = jy0; sx0 = jx0; sy1 = jy1; sx1 = jx1; sa = ja;
                    my_score = __uint_as_float((unsigned)jsc);
                    my_idx = (int)(~(unsigned)jid);
                }
                if (++n_sel == MAX_PER_CLASS) break;
                bool sup = iou_sup(jy0, jx0, jy1, jx1, ja, cb.x, cb.y, cb.z, cb.w, ca);
                supm |= __ballot(sup);
                supm |= 1ull << j; // self (iou=1 also triggers; explicit for clarity)
            }
            pos += blk;
        }
    };

    // Build candidate list from a bitmap: deterministic ascending-n order, then score-gather.
    // Returns count, or -1 on (statistically impossible) overflow.
    auto load_tier = [&](const unsigned long long* bm) -> int {
        unsigned long long wd = 0ull;
        if (lane < NCH) wd = bm[(size_t)(b * NCH + lane) * C_CLS + c];
        int cntl = __popcll(wd);
        int incl = cntl;
#pragma unroll
        for (int off = 1; off < 64; off <<= 1) {
            int v = __shfl_up(incl, off);
            if (lane >= off) incl += v;
        }
        int total = __builtin_amdgcn_readlane(incl, 63);
        if (total > FCAP) return -1;
        int basep = incl - cntl;
        unsigned long long ww = wd;
        int r = 0;
        while (ww) {
            int bit = __ffsll((unsigned long long)ww) - 1;
            ww &= ww - 1;
            buf[basep + r] = (unsigned long long)(unsigned)(lane * 64 + bit);
            ++r;
        }
        __builtin_amdgcn_wave_barrier();
        const float* sp = scores + ((size_t)b * N_BOX) * C_CLS + c;
        for (int i = lane; i < total; i += 64) {
            int n = (int)buf[i];
            float s = sp[(size_t)n * C_CLS]; // scattered, L2/L3-resident
            buf[i] = ((unsigned long long)__float_as_uint(s) << 32) | (unsigned)(~(unsigned)n);
        }
        __builtin_amdgcn_wave_barrier();
        return total;
    };

    auto sort_n = [&](int cnt) {
        if (cnt <= 128)      sort_buf<2>(buf, cnt, lane);
        else if (cnt <= 256) sort_buf<4>(buf, cnt, lane);
        else                 sort_buf<8>(buf, cnt, lane);
    };

    int dirtyStart = -1;
    {
        int cnt1 = load_tier(bm1);
        if (cnt1 < 0) dirtyStart = 0;
        else {
            if (cnt1 > 0) { sort_n(cnt1); process(cnt1); }
            if (n_sel < MAX_PER_CLASS) {
                int cnt2 = load_tier(bm2);
                if (cnt2 < 0) dirtyStart = 1;
                else {
                    if (cnt2 > 0) { sort_n(cnt2); process(cnt2); }
                    if (n_sel < MAX_PER_CLASS) dirtyStart = 2; // below T2
                }
            }
        }
    }
    // fallback tiers via strided rescan (statistically never; correctness-required)
    for (int t = (dirtyStart < 0) ? 6 : dirtyStart; t < 6 && n_sel < MAX_PER_CLASS; ++t) {
        float lo = d_flo[t];
        float hi = (t == 0) ? 3.0e38f : d_flo[t - 1];
        const float* sp = scores + ((size_t)b * N_BOX) * C_CLS + c;
        int cnt = 0;
        for (int ch = 0; ch < N_BOX / 64; ++ch) {
            int n = ch * 64 + lane;
            float s = sp[(size_t)n * C_CLS];
            bool in = (s >= lo) && (s < hi);
            unsigned long long m = __ballot(in);
            if (in) {
                int p = cnt + (int)__popcll(m & lmlt);
                if (p < FCAP)
                    buf[p] = ((unsigned long long)__float_as_uint(s) << 32) |
                             (unsigned)(~(unsigned)n);
            }
            cnt += (int)__popcll(m);
        }
        if (cnt > FCAP) cnt = FCAP;
        if (cnt > 0) { sort_n(cnt); process(cnt); }
    }

    if (lane < MAX_PER_CLASS) {
        size_t base = (size_t)cl * MAX_PER_CLASS + lane;
        cls_score[base] = my_score; // lanes >= n_sel keep -1 (invalid)
        cls_idx[base] = my_idx;
    }
}

// ---------------- Kernel C: per-image top-50 merge + outputs ----------------
__global__ __launch_bounds__(256) void finalize_kernel(const float* __restrict__ cls_score,
                                                       const int* __restrict__ cls_idx,
                                                       const float4* __restrict__ boxes,
                                                       float* __restrict__ out) {
    const int b = blockIdx.x, t = threadIdx.x;
    const int lane = t & 63, wid = t >> 6;
    __shared__ unsigned long long wtop[4 * MAX_TOTAL];
    __shared__ unsigned long long res[MAX_TOTAL];
    unsigned long long k[16];
    const float* cs = cls_score + (size_t)b * (C_CLS * MAX_PER_CLASS);
#pragma unroll
    for (int j = 0; j < 16; ++j) {
        int flat = j * 256 + t;
        float s = (flat < C_CLS * MAX_PER_CLASS) ? cs[flat] : -1.0f;
        k[j] = (s > 0.0f) ? (((unsigned long long)__float_as_uint(s) << 32) |
                             (unsigned)(~(unsigned)flat))
                          : 0ull;
    }
    for (int iter = 0; iter < MAX_TOTAL; ++iter) {
        unsigned long long m = 0ull;
#pragma unroll
        for (int j = 0; j < 16; ++j)
            if (k[j] > m) m = k[j];
#pragma unroll
        for (int off = 32; off; off >>= 1) {
            unsigned long long o = __shfl_xor(m, off);
            if (o > m) m = o;
        }
        if (m == 0ull) {
            for (int r2 = iter + lane; r2 < MAX_TOTAL; r2 += 64) wtop[wid * MAX_TOTAL + r2] = 0ull;
            break;
        }
        if (lane == 0) wtop[wid * MAX_TOTAL + iter] = m;
#pragma unroll
        for (int j = 0; j < 16; ++j)
            if (k[j] == m) k[j] = 0ull;
    }
    __syncthreads();
    if (wid == 0) {
        if (lane < MAX_TOTAL) res[lane] = 0ull;
        unsigned long long lk[4];
        int rk[4];
#pragma unroll
        for (int r = 0; r < 4; ++r) {
            int slot = r * 64 + lane;
            lk[r] = (slot < 4 * MAX_TOTAL) ? wtop[slot] : 0ull;
            rk[r] = 0;
        }
        for (int j = 0; j < 4 * MAX_TOTAL; ++j) {
            unsigned long long kj = wtop[j];
#pragma unroll
            for (int r = 0; r < 4; ++r) rk[r] += (lk[r] < kj) ? 1 : 0;
        }
        __builtin_amdgcn_wave_barrier();
#pragma unroll
        for (int r = 0; r < 4; ++r)
            if (lk[r] != 0ull && rk[r] < MAX_TOTAL) res[rk[r]] = lk[r];
    }
    if (t < 64) {
        unsigned long long key = (t < MAX_TOTAL) ? res[t] : 0ull;
        bool valid = key != 0ull;
        float s = __uint_as_float((unsigned)(key >> 32));
        unsigned flat = ~(unsigned)key;
        int c = valid ? (int)(flat / 50u) : 0;
        int bidx = valid ? cls_idx[(size_t)b * (C_CLS * MAX_PER_CLASS) + flat] : 0;
        float4 bx = boxes[(size_t)b * N_BOX + bidx];
        float o0 = fminf(fmaxf(bx.x, 0.f), 1.f);
        float o1 = fminf(fmaxf(bx.y, 0.f), 1.f);
        float o2 = fminf(fmaxf(bx.z, 0.f), 1.f);
        float o3 = fminf(fmaxf(bx.w, 0.f), 1.f);
        if (t < MAX_TOTAL) {
            float* ob = out + ((size_t)b * MAX_TOTAL + t) * 4;
            ob[0] = valid ? o0 : 0.f;
            ob[1] = valid ? o1 : 0.f;
            ob[2] = valid ? o2 : 0.f;
            ob[3] = valid ? o3 : 0.f;
            out[B_IMG * MAX_TOTAL * 4 + b * MAX_TOTAL + t] = valid ? s : 0.f;
            out[B_IMG * MAX_TOTAL * 5 + b * MAX_TOTAL + t] = valid ? (float)c : 0.f;
        }
        unsigned long long vb = __ballot(valid);
        if (t == 0) out[B_IMG * MAX_TOTAL * 6 + b] = (float)__popcll(vb);
    }
}

extern "C" void kernel_launch(void* const* d_in, const int* in_sizes, int n_in,
                              void* d_out, int out_size, void* d_ws, size_t ws_size,
                              hipStream_t stream) {
    const float* xywh = (const float*)d_in[0];   // (64,4032,4) f32
    const float* scores = (const float*)d_in[1]; // (64,4032,80) f32
    float* out = (float*)d_out;
    char* ws = (char*)d_ws;

    // ws layout: boxes_dec | bm1 | bm2 | cls_score | cls_idx  (~11.3 MB)
    float4* boxes_dec = (float4*)ws;
    size_t off = (size_t)B_IMG * N_BOX * 4 * sizeof(float);       // 4,128,768
    unsigned long long* bm1 = (unsigned long long*)(ws + off);
    off += (size_t)B_IMG * NCH * C_CLS * 8;                       // +2,580,480
    unsigned long long* bm2 = (unsigned long long*)(ws + off);
    off += (size_t)B_IMG * NCH * C_CLS * 8;                       // +2,580,480
    float* cls_score = (float*)(ws + off);
    off += (size_t)B_IMG * C_CLS * MAX_PER_CLASS * sizeof(float);
    int* cls_idx = (int*)(ws + off);

    fused_decode_filter<<<B_IMG * NCH, 256, 0, stream>>>(
        (const float4*)xywh, (const float4*)scores, boxes_dec, bm1, bm2);
    nms_kernel<<<(B_IMG * C_CLS) / 4, 256, 0, stream>>>(bm1, bm2, scores, boxes_dec,
                                                        cls_score, cls_idx);
    finalize_kernel<<<B_IMG, 256, 0, stream>>>(cls_score, cls_idx, boxes_dec, out);
}